// Round 1
// 140.356 us; speedup vs baseline: 1.0283x; 1.0283x over previous
//
#include <hip/hip_runtime.h>
#include <hip/hip_bf16.h>

// SparseAttention B=1,H=8,S=4096,D=32 fp32; mask [S,S] as int32.
// R13: swapped-operand QK^T (mfma(K,Q)) makes P lane-local per q-row ->
// P LDS round-trip (Ps stores/loads, fence, 18KB LDS) eliminated entirely;
// V pre-permutation adjusted so in-register P feeds PV MFMA directly.
// Mask repack transposed to match (bit = mask[q=l&15][k=..+(l>>4)*4+r]),
// mask apply = sign-extend+AND (2 VALU). Preps fused into ONE kernel
// (launch-gap cut + makes prep cost visible in top-5 counters).
// XCD-chunked swizzle: 64 blocks/XCD = one head -> K/V+mask fit 4MB L2.

#define S_  4096
#define D_  32
#define H_  8

typedef _Float16 half8 __attribute__((ext_vector_type(8)));
typedef __fp16 fp16x2 __attribute__((ext_vector_type(2)));
typedef short short8 __attribute__((ext_vector_type(8)));
typedef short short4v __attribute__((ext_vector_type(4)));
typedef float float4v __attribute__((ext_vector_type(4)));
typedef unsigned short ushort_t;
typedef unsigned int u32;

#if __has_builtin(__builtin_amdgcn_exp2f)
#define EXP2(x) __builtin_amdgcn_exp2f(x)
#else
#define EXP2(x) exp2f(x)
#endif

__device__ inline ushort_t f2h(float x) {
    union { _Float16 h; ushort_t u; } c; c.h = (_Float16)x; return c.u;
}

// ---------------- fused pre-pass ----------------
// blocks [0,512): Q fp16 row-major, scale*log2e folded (8 elems/thread)
// blocks [512,1024): K fp16 frag-major [h][kt][t16][quad][n][j]
// blocks [1024,1536): V fp16 frag-major [h][kt][khalf][dhalf][quad][n][j],
//   rows permuted for in-register P: elem j holds row
//   kt*64 + khalf*32 + (j>>2)*16 + quad*4 + (j&3)
// blocks [1536,2560): mask -> per-lane u16 mlane[qt16][kt][lane];
//   bit (t16*4+r) = mask[qt16*16+(l&15)][kt*64 + t16*16 + (l>>4)*4 + r]
__global__ __launch_bounds__(256)
void prep_all(const float* __restrict__ Q, const float* __restrict__ K,
              const float* __restrict__ V, const int* __restrict__ mask,
              ushort_t* __restrict__ Qh, ushort_t* __restrict__ Kt,
              ushort_t* __restrict__ Vt, ushort_t* __restrict__ mlane)
{
    __shared__ u32 msh[16 * 257];   // 16.4 KB, 257-padded: conflict-free both phases
    const int bx = blockIdx.x;
    const int tid = threadIdx.x;
    union U8 { ushort_t u[8]; short8 v; };

    if (bx < 512) {
        const int e0 = (bx * 256 + tid) * 8;
        const float c = 0.17677669529663687f * 1.4426950408889634f;
        float4 a = *(const float4*)(Q + e0);
        float4 b = *(const float4*)(Q + e0 + 4);
        float f[8] = {a.x*c, a.y*c, a.z*c, a.w*c, b.x*c, b.y*c, b.z*c, b.w*c};
        U8 o;
#pragma unroll
        for (int i = 0; i < 8; ++i) o.u[i] = f2h(f[i]);
        *(short8*)(Qh + e0) = o.v;
    } else if (bx < 1024) {
        const int e0 = ((bx - 512) * 256 + tid) * 8;
        const int n = (e0 >> 3) & 15, quad = (e0 >> 7) & 3, t16 = (e0 >> 9) & 3;
        const int kt = (e0 >> 11) & 63, h = e0 >> 17;
        const int krow = kt * 64 + t16 * 16 + n;
        const float* src = K + ((size_t)h * S_ + krow) * D_ + quad * 8;
        float4 a = *(const float4*)src;
        float4 b = *(const float4*)(src + 4);
        float f[8] = {a.x, a.y, a.z, a.w, b.x, b.y, b.z, b.w};
        U8 o;
#pragma unroll
        for (int i = 0; i < 8; ++i) o.u[i] = f2h(f[i]);
        *(short8*)(Kt + e0) = o.v;
    } else if (bx < 1536) {
        const int e0 = ((bx - 1024) * 256 + tid) * 8;
        const int n = (e0 >> 3) & 15, quad = (e0 >> 7) & 3;
        const int dhalf = (e0 >> 9) & 1, khalf = (e0 >> 10) & 1;
        const int kt = (e0 >> 11) & 63, h = e0 >> 17;
        const int d = dhalf * 16 + n;
        U8 o;
#pragma unroll
        for (int j = 0; j < 8; ++j) {
            // nominal k' = quad*8 + j  ->  actual row (j>>2)*16 + quad*4 + (j&3)
            int krow = kt * 64 + khalf * 32 + (j >> 2) * 16 + quad * 4 + (j & 3);
            o.u[j] = f2h(V[((size_t)h * S_ + krow) * D_ + d]);
        }
        *(short8*)(Vt + e0) = o.v;
    } else {
        const int mb = bx - 1536;              // [0,1024)
        const int qt16 = mb >> 2, cc = mb & 3;
        // phase 1: coalesced int4 reads -> bool bytes in LDS (padded rows)
#pragma unroll
        for (int i = 0; i < 16; ++i) {
            int4 m4 = *(const int4*)(mask + (size_t)(qt16 * 16 + i) * S_ + cc * 1024 + tid * 4);
            u32 v = (m4.x != 0 ? 1u : 0u) | (m4.y != 0 ? 0x100u : 0u)
                  | (m4.z != 0 ? 0x10000u : 0u) | (m4.w != 0 ? 0x1000000u : 0u);
            msh[i * 257 + tid] = v;
        }
        __syncthreads();
        // phase 2: thread -> 4 u16 words = lanes g*4..g*4+3 of one kt.
        // lane l = g*4+b: row = (g&3)*4+b, quad_l = g>>2.
        const int kt_local = tid >> 4, g = tid & 15;
        const int qd = g >> 2, n4 = g & 3;
        u32 o16[4] = {0, 0, 0, 0};
#pragma unroll
        for (int t16 = 0; t16 < 4; ++t16) {
            const int cbase = kt_local * 16 + t16 * 4 + qd;
#pragma unroll
            for (int b = 0; b < 4; ++b) {
                u32 v = msh[(n4 * 4 + b) * 257 + cbase];
                // bytes {0,1} -> nibble b0|b1<<1|b2<<2|b3<<3 (no carries)
                u32 nib = ((v * 0x01020408u) >> 24) & 0xFu;
                o16[b] |= nib << (t16 * 4);
            }
        }
        union { u32 w2[2]; short4v s; } pk;
        pk.w2[0] = o16[0] | (o16[1] << 16);
        pk.w2[1] = o16[2] | (o16[3] << 16);
        const int kt = cc * 16 + kt_local;
        *(short4v*)(mlane + ((size_t)(qt16 * 64 + kt) * 64 + g * 4)) = pk.s;
    }
}

// ---------------- main MFMA flash kernel (8 waves, dbuf staging) ---------

__device__ inline void gl_lds16(const ushort_t* g, ushort_t* l) {
    __builtin_amdgcn_global_load_lds((const __attribute__((address_space(1))) void*)g,
                                     (__attribute__((address_space(3))) void*)l,
                                     16, 0, 0);
}

__global__ __launch_bounds__(512, 2)
void attn_mfma(const ushort_t* __restrict__ Qh, const ushort_t* __restrict__ Kt,
               const ushort_t* __restrict__ Vt, const ushort_t* __restrict__ mlane,
               float* __restrict__ out)
{
    // K_s [half][buf][2048] 16KB | V_s same 16KB. No P staging (in-register).
    __shared__ __align__(16) ushort_t sm[16384];
    ushort_t* K_s  = sm;
    ushort_t* Vt_s = sm + 8192;

    // XCD-chunked swizzle: 512 blocks = 8 XCDs x 64; each XCD gets one head.
    const int bid = blockIdx.x;
    const int swz = (bid & 7) * 64 + (bid >> 3);
    const int h  = swz >> 6;
    const int qb = swz & 63;
    const int q0 = qb * 64;

    const int tid = threadIdx.x;
    const int w = tid >> 6, l = tid & 63;
    const int half = w >> 2, wl = w & 3;
    const int n16 = l & 15, quad = l >> 4;

    const int qt16_u = __builtin_amdgcn_readfirstlane(qb * 4 + wl);
    const ushort_t* mlw = mlane + ((size_t)qt16_u << 12);  // [kt][lane]

    const int qrow = q0 + wl * 16 + n16;
    const half8 qh = *(const half8*)(Qh + ((size_t)h * S_ + qrow) * D_ + quad * 8);

    half8 ones;
#pragma unroll
    for (int i = 0; i < 8; ++i) ones[i] = (_Float16)1.0f;

    float4v o0 = {0.f, 0.f, 0.f, 0.f};
    float4v o1 = {0.f, 0.f, 0.f, 0.f};
    float4v lacc = {0.f, 0.f, 0.f, 0.f};

    const int hb = half * 4096;
    const int kt_base = half * 32;

    // prologue: stage first tile into buf 0
    {
        const size_t tb = ((size_t)(h * 64 + kt_base)) * 2048 + wl * 512 + l * 8;
        gl_lds16(Kt + tb, K_s  + hb + wl * 512);
        gl_lds16(Vt + tb, Vt_s + hb + wl * 512);
    }
    __syncthreads();

    for (int i = 0; i < 32; ++i) {
        const int kt = kt_base + i;
        const int cb = hb + (i & 1) * 2048;        // current buffer
        if (i < 31) {
            const int nb = hb + ((i + 1) & 1) * 2048;
            const size_t tb = ((size_t)(h * 64 + kt + 1)) * 2048 + wl * 512 + l * 8;
            gl_lds16(Kt + tb, K_s  + nb + wl * 512);
            gl_lds16(Vt + tb, Vt_s + nb + wl * 512);
        }

        const u32 ml = mlw[kt * 64 + l];   // 16 mask bits for q=l&15, k-cols of this lane

        float pv[4][4];
#pragma unroll
        for (int t16 = 0; t16 < 4; ++t16) {
            const half8 kb = *(const half8*)(K_s + cb + (t16 * 4 + quad) * 128 + n16 * 8);
            float4v c = {0.f, 0.f, 0.f, 0.f};
            // SWAPPED: D[kpos][q] -> lane holds 4 kpos for its q=l&15
            c = __builtin_amdgcn_mfma_f32_16x16x32_f16(kb, qh, c, 0, 0, 0);
#pragma unroll
            for (int r = 0; r < 4; ++r) {
                float e = EXP2(c[r]);
                const int bp = t16 * 4 + r;
                u32 keep = (u32)((int)(ml << (31 - bp)) >> 31);   // bfe-style all-ones/0
                pv[t16][r] = __uint_as_float(__float_as_uint(e) & keep);
            }
        }

        // P stays in registers: pa[j = tt*4+r] = pv[2*kh+tt][r]
#pragma unroll
        for (int kh = 0; kh < 2; ++kh) {
            union { fp16x2 hh[4]; half8 h8; } pk;
            pk.hh[0] = __builtin_amdgcn_cvt_pkrtz(pv[2*kh][0],   pv[2*kh][1]);
            pk.hh[1] = __builtin_amdgcn_cvt_pkrtz(pv[2*kh][2],   pv[2*kh][3]);
            pk.hh[2] = __builtin_amdgcn_cvt_pkrtz(pv[2*kh+1][0], pv[2*kh+1][1]);
            pk.hh[3] = __builtin_amdgcn_cvt_pkrtz(pv[2*kh+1][2], pv[2*kh+1][3]);
            const half8 pa = pk.h8;
            const half8 v0 = *(const half8*)(Vt_s + cb + ((kh * 2 + 0) * 4 + quad) * 128 + n16 * 8);
            const half8 v1 = *(const half8*)(Vt_s + cb + ((kh * 2 + 1) * 4 + quad) * 128 + n16 * 8);
            o0   = __builtin_amdgcn_mfma_f32_16x16x32_f16(pa, v0,   o0,   0, 0, 0);
            o1   = __builtin_amdgcn_mfma_f32_16x16x32_f16(pa, v1,   o1,   0, 0, 0);
            lacc = __builtin_amdgcn_mfma_f32_16x16x32_f16(pa, ones, lacc, 0, 0, 0);
        }

        // one barrier per iter: next-buf staging drained AND cur-buf reads done
        __syncthreads();
    }

    // ---- block-level combine: half 1 dumps partials, half 0 reduces+stores
    // o0[r]: O[q=quad*4+r][d=n16], o1: d=16+n16, lacc[r]: l-sum (same as R12)
    float* red = (float*)sm;            // reuse staging area (8.7KB < 32KB)
    const int RSTR = 16 * 33 + 16;      // per-wl region: o[16][33] + l[16]
    if (half == 1) {
        float* ro = red + wl * RSTR;
#pragma unroll
        for (int reg = 0; reg < 4; ++reg) {
            const int r = quad * 4 + reg;
            ro[r * 33 + n16]      = o0[reg];
            ro[r * 33 + 16 + n16] = o1[reg];
            if (n16 == 0) ro[16 * 33 + r] = lacc[reg];
        }
    }
    __syncthreads();
    if (half == 0) {
        const float* ro = red + wl * RSTR;
#pragma unroll
        for (int reg = 0; reg < 4; ++reg) {
            const int r = quad * 4 + reg;
            const float inv = 1.0f / (lacc[reg] + ro[16 * 33 + r]); // band => >0
            const int row = q0 + wl * 16 + r;
            float* orow = out + ((size_t)h * S_ + row) * D_;
            orow[n16]      = (o0[reg] + ro[r * 33 + n16]) * inv;
            orow[16 + n16] = (o1[reg] + ro[r * 33 + 16 + n16]) * inv;
        }
    }
}

// ---------------- fallback fp32 kernel (proven) ----------------

#define QT 64
#define KT 64
#define NSUB 4
#define KPT 16

__global__ __launch_bounds__(256, 2)
void sparse_attn_fp32(const float* __restrict__ Q, const float* __restrict__ K,
                      const float* __restrict__ V, const int* __restrict__ mask,
                      float* __restrict__ out)
{
    __shared__ float Ks[KT][D_];
    __shared__ float Vs[KT][D_];
    __shared__ float red_o[NSUB][QT][D_ + 1];
    __shared__ float red_l[NSUB][QT];

    const int h = blockIdx.y;
    const int q0 = blockIdx.x * QT;
    const int tid = threadIdx.x;
    const int ql = tid & 63;
    const int sub = tid >> 6;
    const int q = q0 + ql;
    const float scale = 0.17677669529663687f;

    float4 qreg[8];
    const float4* qrow = (const float4*)(Q + ((size_t)h * S_ + q) * D_);
#pragma unroll
    for (int i = 0; i < 8; ++i) qreg[i] = qrow[i];

    float o[D_];
#pragma unroll
    for (int d = 0; d < D_; ++d) o[d] = 0.f;
    float lsum0 = 0.f;

    const float* Kh = K + (size_t)h * S_ * D_;
    const float* Vh = V + (size_t)h * S_ * D_;

    for (int jt = 0; jt < S_; jt += KT) {
        __syncthreads();
        {
            const float4* gK = (const float4*)(Kh + (size_t)jt * D_);
            const float4* gV = (const float4*)(Vh + (size_t)jt * D_);
            float4* sK = (float4*)&Ks[0][0];
            float4* sV = (float4*)&Vs[0][0];
            sK[tid] = gK[tid]; sK[tid + 256] = gK[tid + 256];
            sV[tid] = gV[tid]; sV[tid + 256] = gV[tid + 256];
        }
        __syncthreads();

        int4 m4[4];
        {
            const int4* mr = (const int4*)(mask + (size_t)q * S_ + jt + sub * KPT);
#pragma unroll
            for (int i = 0; i < 4; ++i) m4[i] = mr[i];
        }
        const int* mb = (const int*)m4;

#pragma unroll
        for (int kk = 0; kk < KPT; ++kk) {
            const int jl = sub * KPT + kk;
            const float4* krow = (const float4*)&Ks[jl][0];
            float s = 0.f;
#pragma unroll
            for (int i = 0; i < 8; ++i) {
                float4 kv = krow[i];
                s += qreg[i].x * kv.x + qreg[i].y * kv.y + qreg[i].z * kv.z + qreg[i].w * kv.w;
            }
            const float p = mb[kk] ? __expf(s * scale) : 0.f;
            lsum0 += p;
            const float4* vrow = (const float4*)&Vs[jl][0];
#pragma unroll
            for (int i = 0; i < 8; ++i) {
                float4 vv = vrow[i];
                o[i * 4 + 0] += p * vv.x;
                o[i * 4 + 1] += p * vv.y;
                o[i * 4 + 2] += p * vv.z;
                o[i * 4 + 3] += p * vv.w;
            }
        }
    }

#pragma unroll
    for (int d = 0; d < D_; ++d) red_o[sub][ql][d] = o[d];
    red_l[sub][ql] = lsum0;
    __syncthreads();

    const int eq = tid & 63;
    const int dg = tid >> 6;
    float acc[8];
#pragma unroll
    for (int i = 0; i < 8; ++i) acc[i] = 0.f;
    float lsum = 0.f;
#pragma unroll
    for (int s2 = 0; s2 < NSUB; ++s2) {
        lsum += red_l[s2][eq];
#pragma unroll
        for (int i = 0; i < 8; ++i) acc[i] += red_o[s2][eq][dg * 8 + i];
    }
    const float inv = 1.0f / lsum;
    float* orow = out + ((size_t)h * S_ + q0 + eq) * D_ + dg * 8;
#pragma unroll
    for (int i = 0; i < 8; ++i) orow[i] = acc[i] * inv;
}

// ---------------- host ----------------

extern "C" void kernel_launch(void* const* d_in, const int* in_sizes, int n_in,
                              void* d_out, int out_size, void* d_ws, size_t ws_size,
                              hipStream_t stream) {
    const float* Q = (const float*)d_in[0];
    const float* K = (const float*)d_in[1];
    const float* V = (const float*)d_in[2];
    const int* mask = (const int*)d_in[3];
    float* out = (float*)d_out;

    const size_t MB = 1024 * 1024;
    if (ws_size < 8 * MB) {
        dim3 grid(S_ / QT, H_);
        sparse_attn_fp32<<<grid, 256, 0, stream>>>(Q, K, V, mask, out);
        return;
    }

    char* ws = (char*)d_ws;
    ushort_t* Qh = (ushort_t*)(ws + 0 * MB);
    ushort_t* Kt = (ushort_t*)(ws + 2 * MB);
    ushort_t* Vt = (ushort_t*)(ws + 4 * MB);
    ushort_t* mlane = (ushort_t*)(ws + 6 * MB);  // 2 MB

    prep_all<<<2560, 256, 0, stream>>>(Q, K, V, mask, Qh, Kt, Vt, mlane);
    attn_mfma<<<512, 512, 0, stream>>>(Qh, Kt, Vt, mlane, out);
}

// Round 2
// 139.702 us; speedup vs baseline: 1.0331x; 1.0047x over previous
//
#include <hip/hip_runtime.h>
#include <hip/hip_bf16.h>

// SparseAttention B=1,H=8,S=4096,D=32 fp32; mask [S,S] as int32.
// R14: occupancy push. attn: 512 blocks x 1024 thr (16 waves), q-tile 64,
// k split 4 ways (kq 0..3, 16 kt each) -> 2 blocks/CU x 1024 thr = 100%
// occupancy (was 50% cap), serial chain halved (16 iters). LDS 64KB/block
// (4 kq x dbuf x {K,V} 4KB tiles), 4-way combine epilogue in reused LDS.
// Mask bit extract via v_bfe_i32. Prep unchanged (R13 fused prep_all).
// R13 lessons kept: swapped-operand QK^T (P lane-local, no P LDS trip),
// V pre-permuted for in-register P, XCD-chunked swizzle (head per XCD).

#define S_  4096
#define D_  32
#define H_  8

typedef _Float16 half8 __attribute__((ext_vector_type(8)));
typedef __fp16 fp16x2 __attribute__((ext_vector_type(2)));
typedef short short8 __attribute__((ext_vector_type(8)));
typedef short short4v __attribute__((ext_vector_type(4)));
typedef float float4v __attribute__((ext_vector_type(4)));
typedef unsigned short ushort_t;
typedef unsigned int u32;

#if __has_builtin(__builtin_amdgcn_exp2f)
#define EXP2(x) __builtin_amdgcn_exp2f(x)
#else
#define EXP2(x) exp2f(x)
#endif

#if __has_builtin(__builtin_amdgcn_sbfe)
#define SEXT_BIT(v, b) ((u32)__builtin_amdgcn_sbfe((int)(v), (b), 1))
#else
#define SEXT_BIT(v, b) ((u32)(((int)((v) << (31 - (b)))) >> 31))
#endif

__device__ inline ushort_t f2h(float x) {
    union { _Float16 h; ushort_t u; } c; c.h = (_Float16)x; return c.u;
}

// ---------------- fused pre-pass ----------------
// blocks [0,512): Q fp16 row-major, scale*log2e folded (8 elems/thread)
// blocks [512,1024): K fp16 frag-major [h][kt][t16][quad][n][j]
// blocks [1024,1536): V fp16 frag-major [h][kt][khalf][dhalf][quad][n][j],
//   rows permuted for in-register P: elem j holds row
//   kt*64 + khalf*32 + (j>>2)*16 + quad*4 + (j&3)
// blocks [1536,2560): mask -> per-lane u16 mlane[qt16][kt][lane];
//   bit (t16*4+r) = mask[qt16*16+(l&15)][kt*64 + t16*16 + (l>>4)*4 + r]
__global__ __launch_bounds__(256)
void prep_all(const float* __restrict__ Q, const float* __restrict__ K,
              const float* __restrict__ V, const int* __restrict__ mask,
              ushort_t* __restrict__ Qh, ushort_t* __restrict__ Kt,
              ushort_t* __restrict__ Vt, ushort_t* __restrict__ mlane)
{
    __shared__ u32 msh[16 * 257];   // 16.4 KB, 257-padded: conflict-free both phases
    const int bx = blockIdx.x;
    const int tid = threadIdx.x;
    union U8 { ushort_t u[8]; short8 v; };

    if (bx < 512) {
        const int e0 = (bx * 256 + tid) * 8;
        const float c = 0.17677669529663687f * 1.4426950408889634f;
        float4 a = *(const float4*)(Q + e0);
        float4 b = *(const float4*)(Q + e0 + 4);
        float f[8] = {a.x*c, a.y*c, a.z*c, a.w*c, b.x*c, b.y*c, b.z*c, b.w*c};
        U8 o;
#pragma unroll
        for (int i = 0; i < 8; ++i) o.u[i] = f2h(f[i]);
        *(short8*)(Qh + e0) = o.v;
    } else if (bx < 1024) {
        const int e0 = ((bx - 512) * 256 + tid) * 8;
        const int n = (e0 >> 3) & 15, quad = (e0 >> 7) & 3, t16 = (e0 >> 9) & 3;
        const int kt = (e0 >> 11) & 63, h = e0 >> 17;
        const int krow = kt * 64 + t16 * 16 + n;
        const float* src = K + ((size_t)h * S_ + krow) * D_ + quad * 8;
        float4 a = *(const float4*)src;
        float4 b = *(const float4*)(src + 4);
        float f[8] = {a.x, a.y, a.z, a.w, b.x, b.y, b.z, b.w};
        U8 o;
#pragma unroll
        for (int i = 0; i < 8; ++i) o.u[i] = f2h(f[i]);
        *(short8*)(Kt + e0) = o.v;
    } else if (bx < 1536) {
        const int e0 = ((bx - 1024) * 256 + tid) * 8;
        const int n = (e0 >> 3) & 15, quad = (e0 >> 7) & 3;
        const int dhalf = (e0 >> 9) & 1, khalf = (e0 >> 10) & 1;
        const int kt = (e0 >> 11) & 63, h = e0 >> 17;
        const int d = dhalf * 16 + n;
        U8 o;
#pragma unroll
        for (int j = 0; j < 8; ++j) {
            // nominal k' = quad*8 + j  ->  actual row (j>>2)*16 + quad*4 + (j&3)
            int krow = kt * 64 + khalf * 32 + (j >> 2) * 16 + quad * 4 + (j & 3);
            o.u[j] = f2h(V[((size_t)h * S_ + krow) * D_ + d]);
        }
        *(short8*)(Vt + e0) = o.v;
    } else {
        const int mb = bx - 1536;              // [0,1024)
        const int qt16 = mb >> 2, cc = mb & 3;
        // phase 1: coalesced int4 reads -> bool bytes in LDS (padded rows)
#pragma unroll
        for (int i = 0; i < 16; ++i) {
            int4 m4 = *(const int4*)(mask + (size_t)(qt16 * 16 + i) * S_ + cc * 1024 + tid * 4);
            u32 v = (m4.x != 0 ? 1u : 0u) | (m4.y != 0 ? 0x100u : 0u)
                  | (m4.z != 0 ? 0x10000u : 0u) | (m4.w != 0 ? 0x1000000u : 0u);
            msh[i * 257 + tid] = v;
        }
        __syncthreads();
        // phase 2: thread -> 4 u16 words = lanes g*4..g*4+3 of one kt.
        const int kt_local = tid >> 4, g = tid & 15;
        const int qd = g >> 2, n4 = g & 3;
        u32 o16[4] = {0, 0, 0, 0};
#pragma unroll
        for (int t16 = 0; t16 < 4; ++t16) {
            const int cbase = kt_local * 16 + t16 * 4 + qd;
#pragma unroll
            for (int b = 0; b < 4; ++b) {
                u32 v = msh[(n4 * 4 + b) * 257 + cbase];
                // bytes {0,1} -> nibble b0|b1<<1|b2<<2|b3<<3 (no carries)
                u32 nib = ((v * 0x01020408u) >> 24) & 0xFu;
                o16[b] |= nib << (t16 * 4);
            }
        }
        union { u32 w2[2]; short4v s; } pk;
        pk.w2[0] = o16[0] | (o16[1] << 16);
        pk.w2[1] = o16[2] | (o16[3] << 16);
        const int kt = cc * 16 + kt_local;
        *(short4v*)(mlane + ((size_t)(qt16 * 64 + kt) * 64 + g * 4)) = pk.s;
    }
}

// ---------------- main MFMA flash kernel (16 waves, 4-way k-split) -------

__device__ inline void gl_lds16(const ushort_t* g, ushort_t* l) {
    __builtin_amdgcn_global_load_lds((const __attribute__((address_space(1))) void*)g,
                                     (__attribute__((address_space(3))) void*)l,
                                     16, 0, 0);
}

__global__ __launch_bounds__(1024, 8)
void attn_mfma(const ushort_t* __restrict__ Qh, const ushort_t* __restrict__ Kt,
               const ushort_t* __restrict__ Vt, const ushort_t* __restrict__ mlane,
               float* __restrict__ out)
{
    // K_s [kq][buf][2048] 32KB | V_s same 32KB. 64KB total; 2 blocks/CU.
    __shared__ __align__(16) ushort_t sm[32768];
    ushort_t* K_s  = sm;
    ushort_t* Vt_s = sm + 16384;

    // XCD-chunked swizzle: 512 blocks = 8 XCDs x 64; each XCD gets one head.
    const int bid = blockIdx.x;
    const int swz = (bid & 7) * 64 + (bid >> 3);
    const int h  = swz >> 6;
    const int qb = swz & 63;
    const int q0 = qb * 64;

    const int tid = threadIdx.x;
    const int w = tid >> 6, l = tid & 63;
    const int kq = w >> 2, wl = w & 3;      // k-quarter, q-subtile
    const int n16 = l & 15, quad = l >> 4;

    const int qt16_u = __builtin_amdgcn_readfirstlane(qb * 4 + wl);
    const ushort_t* mlw = mlane + ((size_t)qt16_u << 12);  // [kt][lane]

    const int qrow = q0 + wl * 16 + n16;
    const half8 qh = *(const half8*)(Qh + ((size_t)h * S_ + qrow) * D_ + quad * 8);

    half8 ones;
#pragma unroll
    for (int i = 0; i < 8; ++i) ones[i] = (_Float16)1.0f;

    float4v o0 = {0.f, 0.f, 0.f, 0.f};
    float4v o1 = {0.f, 0.f, 0.f, 0.f};
    float4v lacc = {0.f, 0.f, 0.f, 0.f};

    const int gb = kq * 4096;               // this k-group's LDS region
    const int kt_base = kq * 16;

    // prologue: stage first tile into buf 0
    {
        const size_t tb = ((size_t)(h * 64 + kt_base)) * 2048 + wl * 512 + l * 8;
        gl_lds16(Kt + tb, K_s  + gb + wl * 512);
        gl_lds16(Vt + tb, Vt_s + gb + wl * 512);
    }
    __syncthreads();

    for (int i = 0; i < 16; ++i) {
        const int kt = kt_base + i;
        const int cb = gb + (i & 1) * 2048;        // current buffer
        if (i < 15) {
            const int nb = gb + ((i + 1) & 1) * 2048;
            const size_t tb = ((size_t)(h * 64 + kt + 1)) * 2048 + wl * 512 + l * 8;
            gl_lds16(Kt + tb, K_s  + nb + wl * 512);
            gl_lds16(Vt + tb, Vt_s + nb + wl * 512);
        }

        const u32 ml = mlw[kt * 64 + l];   // 16 mask bits for q=l&15 of this lane

        float pv[4][4];
#pragma unroll
        for (int t16 = 0; t16 < 4; ++t16) {
            const half8 kb = *(const half8*)(K_s + cb + (t16 * 4 + quad) * 128 + n16 * 8);
            float4v c = {0.f, 0.f, 0.f, 0.f};
            // SWAPPED: D[kpos][q] -> lane holds 4 kpos for its q=l&15
            c = __builtin_amdgcn_mfma_f32_16x16x32_f16(kb, qh, c, 0, 0, 0);
#pragma unroll
            for (int r = 0; r < 4; ++r) {
                float e = EXP2(c[r]);
                u32 keep = SEXT_BIT(ml, t16 * 4 + r);     // all-ones or 0
                pv[t16][r] = __uint_as_float(__float_as_uint(e) & keep);
            }
        }

        // P stays in registers: pa[j = tt*4+r] = pv[2*kh+tt][r]
#pragma unroll
        for (int kh = 0; kh < 2; ++kh) {
            union { fp16x2 hh[4]; half8 h8; } pk;
            pk.hh[0] = __builtin_amdgcn_cvt_pkrtz(pv[2*kh][0],   pv[2*kh][1]);
            pk.hh[1] = __builtin_amdgcn_cvt_pkrtz(pv[2*kh][2],   pv[2*kh][3]);
            pk.hh[2] = __builtin_amdgcn_cvt_pkrtz(pv[2*kh+1][0], pv[2*kh+1][1]);
            pk.hh[3] = __builtin_amdgcn_cvt_pkrtz(pv[2*kh+1][2], pv[2*kh+1][3]);
            const half8 pa = pk.h8;
            const half8 v0 = *(const half8*)(Vt_s + cb + ((kh * 2 + 0) * 4 + quad) * 128 + n16 * 8);
            const half8 v1 = *(const half8*)(Vt_s + cb + ((kh * 2 + 1) * 4 + quad) * 128 + n16 * 8);
            o0   = __builtin_amdgcn_mfma_f32_16x16x32_f16(pa, v0,   o0,   0, 0, 0);
            o1   = __builtin_amdgcn_mfma_f32_16x16x32_f16(pa, v1,   o1,   0, 0, 0);
            lacc = __builtin_amdgcn_mfma_f32_16x16x32_f16(pa, ones, lacc, 0, 0, 0);
        }

        // one barrier per iter: next-buf staging drained AND cur-buf reads done
        __syncthreads();
    }

    // ---- block-level combine: kq 1..3 dump partials, kq 0 reduces+stores
    // o0[r]: O[q=quad*4+r][d=n16], o1: d=16+n16, lacc[r]: l-sum
    float* red = (float*)sm;            // reuse staging area (26KB < 64KB)
    const int RSTR = 16 * 33 + 16;      // per-region: o[16][33] + l[16]
    if (kq != 0) {
        float* ro = red + ((kq - 1) * 4 + wl) * RSTR;
#pragma unroll
        for (int reg = 0; reg < 4; ++reg) {
            const int r = quad * 4 + reg;
            ro[r * 33 + n16]      = o0[reg];
            ro[r * 33 + 16 + n16] = o1[reg];
            if (n16 == 0) ro[16 * 33 + r] = lacc[reg];
        }
    }
    __syncthreads();
    if (kq == 0) {
#pragma unroll
        for (int reg = 0; reg < 4; ++reg) {
            const int r = quad * 4 + reg;
            float s0 = o0[reg], s1 = o1[reg], sl = lacc[reg];
#pragma unroll
            for (int p = 0; p < 3; ++p) {
                const float* ro = red + (p * 4 + wl) * RSTR;
                s0 += ro[r * 33 + n16];
                s1 += ro[r * 33 + 16 + n16];
                sl += ro[16 * 33 + r];
            }
            const float inv = 1.0f / sl;               // band => >0
            const int row = q0 + wl * 16 + r;
            float* orow = out + ((size_t)h * S_ + row) * D_;
            orow[n16]      = s0 * inv;
            orow[16 + n16] = s1 * inv;
        }
    }
}

// ---------------- fallback fp32 kernel (proven) ----------------

#define QT 64
#define KT 64
#define NSUB 4
#define KPT 16

__global__ __launch_bounds__(256, 2)
void sparse_attn_fp32(const float* __restrict__ Q, const float* __restrict__ K,
                      const float* __restrict__ V, const int* __restrict__ mask,
                      float* __restrict__ out)
{
    __shared__ float Ks[KT][D_];
    __shared__ float Vs[KT][D_];
    __shared__ float red_o[NSUB][QT][D_ + 1];
    __shared__ float red_l[NSUB][QT];

    const int h = blockIdx.y;
    const int q0 = blockIdx.x * QT;
    const int tid = threadIdx.x;
    const int ql = tid & 63;
    const int sub = tid >> 6;
    const int q = q0 + ql;
    const float scale = 0.17677669529663687f;

    float4 qreg[8];
    const float4* qrow = (const float4*)(Q + ((size_t)h * S_ + q) * D_);
#pragma unroll
    for (int i = 0; i < 8; ++i) qreg[i] = qrow[i];

    float o[D_];
#pragma unroll
    for (int d = 0; d < D_; ++d) o[d] = 0.f;
    float lsum0 = 0.f;

    const float* Kh = K + (size_t)h * S_ * D_;
    const float* Vh = V + (size_t)h * S_ * D_;

    for (int jt = 0; jt < S_; jt += KT) {
        __syncthreads();
        {
            const float4* gK = (const float4*)(Kh + (size_t)jt * D_);
            const float4* gV = (const float4*)(Vh + (size_t)jt * D_);
            float4* sK = (float4*)&Ks[0][0];
            float4* sV = (float4*)&Vs[0][0];
            sK[tid] = gK[tid]; sK[tid + 256] = gK[tid + 256];
            sV[tid] = gV[tid]; sV[tid + 256] = gV[tid + 256];
        }
        __syncthreads();

        int4 m4[4];
        {
            const int4* mr = (const int4*)(mask + (size_t)q * S_ + jt + sub * KPT);
#pragma unroll
            for (int i = 0; i < 4; ++i) m4[i] = mr[i];
        }
        const int* mb = (const int*)m4;

#pragma unroll
        for (int kk = 0; kk < KPT; ++kk) {
            const int jl = sub * KPT + kk;
            const float4* krow = (const float4*)&Ks[jl][0];
            float s = 0.f;
#pragma unroll
            for (int i = 0; i < 8; ++i) {
                float4 kv = krow[i];
                s += qreg[i].x * kv.x + qreg[i].y * kv.y + qreg[i].z * kv.z + qreg[i].w * kv.w;
            }
            const float p = mb[kk] ? __expf(s * scale) : 0.f;
            lsum0 += p;
            const float4* vrow = (const float4*)&Vs[jl][0];
#pragma unroll
            for (int i = 0; i < 8; ++i) {
                float4 vv = vrow[i];
                o[i * 4 + 0] += p * vv.x;
                o[i * 4 + 1] += p * vv.y;
                o[i * 4 + 2] += p * vv.z;
                o[i * 4 + 3] += p * vv.w;
            }
        }
    }

#pragma unroll
    for (int d = 0; d < D_; ++d) red_o[sub][ql][d] = o[d];
    red_l[sub][ql] = lsum0;
    __syncthreads();

    const int eq = tid & 63;
    const int dg = tid >> 6;
    float acc[8];
#pragma unroll
    for (int i = 0; i < 8; ++i) acc[i] = 0.f;
    float lsum = 0.f;
#pragma unroll
    for (int s2 = 0; s2 < NSUB; ++s2) {
        lsum += red_l[s2][eq];
#pragma unroll
        for (int i = 0; i < 8; ++i) acc[i] += red_o[s2][eq][dg * 8 + i];
    }
    const float inv = 1.0f / lsum;
    float* orow = out + ((size_t)h * S_ + q0 + eq) * D_ + dg * 8;
#pragma unroll
    for (int i = 0; i < 8; ++i) orow[i] = acc[i] * inv;
}

// ---------------- host ----------------

extern "C" void kernel_launch(void* const* d_in, const int* in_sizes, int n_in,
                              void* d_out, int out_size, void* d_ws, size_t ws_size,
                              hipStream_t stream) {
    const float* Q = (const float*)d_in[0];
    const float* K = (const float*)d_in[1];
    const float* V = (const float*)d_in[2];
    const int* mask = (const int*)d_in[3];
    float* out = (float*)d_out;

    const size_t MB = 1024 * 1024;
    if (ws_size < 8 * MB) {
        dim3 grid(S_ / QT, H_);
        sparse_attn_fp32<<<grid, 256, 0, stream>>>(Q, K, V, mask, out);
        return;
    }

    char* ws = (char*)d_ws;
    ushort_t* Qh = (ushort_t*)(ws + 0 * MB);
    ushort_t* Kt = (ushort_t*)(ws + 2 * MB);
    ushort_t* Vt = (ushort_t*)(ws + 4 * MB);
    ushort_t* mlane = (ushort_t*)(ws + 6 * MB);  // 2 MB

    prep_all<<<2560, 256, 0, stream>>>(Q, K, V, mask, Qh, Kt, Vt, mlane);
    attn_mfma<<<512, 1024, 0, stream>>>(Qh, Kt, Vt, mlane, out);
}